// Round 1
// baseline (1881.522 us; speedup 1.0000x reference)
//
#include <hip/hip_runtime.h>

#define NB 16384
#define DIM 32
#define LS 100
#define KH 50       // hidden width of the param subnet
#define PCOLS 9696  // 3*DIM*LS + 3*DIM
#define WROW 64     // padded row length of W2T (256B-aligned rows)
#define HROW 64     // padded row length of h

// ---- transpose + pad W2 [50,9696] -> W2T [9696,64] (cols padded with 0) ----
__global__ __launch_bounds__(256) void transpose_pad(const float* __restrict__ W2,
                                                     float* __restrict__ W2T) {
    int idx = blockIdx.x * 256 + threadIdx.x;
    if (idx >= PCOLS * WROW) return;
    int k = idx / PCOLS;        // 0..63, k-major so reads are coalesced
    int c = idx - k * PCOLS;    // 0..9695
    float v = (k < KH) ? W2[k * PCOLS + c] : 0.0f;
    W2T[(size_t)c * WROW + k] = v;
}

// ---- h = relu(cond @ W1 + b1); cond is a 32-col slice of a [B,64] matrix ----
__global__ __launch_bounds__(256) void h_kernel(const float* __restrict__ cond, int cond_off,
                                                const float* __restrict__ W1,
                                                const float* __restrict__ b1,
                                                float* __restrict__ h) {
    int i = blockIdx.x * 256 + threadIdx.x;   // sample
    const float* crow = cond + (size_t)i * 64 + cond_off;
    float c[DIM];
#pragma unroll
    for (int j = 0; j < DIM; j++) c[j] = crow[j];
    float* hrow = h + (size_t)i * HROW;
    for (int k = 0; k < KH; k++) {
        float acc = b1[k];
#pragma unroll
        for (int j = 0; j < DIM; j++) acc += c[j] * W1[j * KH + k];
        hrow[k] = fmaxf(acc, 0.0f);
    }
}

// ---- fused p-GEMM + PfndELU epilogue. lane = sample, block = 64 samples x 2 dims ----
__global__ __launch_bounds__(64) void y_kernel(const float* __restrict__ x, int x_off,
                                               const float* __restrict__ h,
                                               const float* __restrict__ W2T,
                                               const float* __restrict__ b2,
                                               float* __restrict__ out, int out_off) {
    int sample = blockIdx.x * 64 + threadIdx.x;
    int d0 = blockIdx.y * 2;

    float hv[KH];
    const float* hrow = h + (size_t)sample * HROW;
#pragma unroll
    for (int k = 0; k < KH; k++) hv[k] = hrow[k];

#pragma unroll
    for (int dd = 0; dd < 2; dd++) {
        int d = d0 + dd;
        float xd = x[(size_t)sample * 64 + x_off + d];
        float num = 0.0f, den = 0.0f;
        for (int l = 0; l < LS; l++) {
            int c = d * LS + l;   // wave-uniform -> scalar loads below
            const float* w1c = W2T + (size_t)c * WROW;
            const float* wb1 = W2T + (size_t)(DIM * LS + c) * WROW;
            const float* w2c = W2T + (size_t)(2 * DIM * LS + c) * WROW;
            float m1 = b2[c];
            float bb1 = b2[DIM * LS + c];
            float m2 = b2[2 * DIM * LS + c];
#pragma unroll
            for (int k = 0; k < KH; k++) {
                m1  += hv[k] * w1c[k];
                bb1 += hv[k] * wb1[k];
                m2  += hv[k] * w2c[k];
            }
            float z = xd * m1 + bb1;
            float e = (z > 0.0f) ? z : (__expf(z) - 1.0f);   // elu
            num += e * m2;
            float t = -m1 * m2;
            den += (t > 0.0f) ? t : 0.0f;                    // relu
        }
        den += 1.0f;

        // tail params: bias2, eps, alpha
        int cb = 3 * DIM * LS + d;
        int ce = 3 * DIM * LS + DIM + d;
        int ca = 3 * DIM * LS + 2 * DIM + d;
        const float* wb2 = W2T + (size_t)cb * WROW;
        const float* we  = W2T + (size_t)ce * WROW;
        const float* wa  = W2T + (size_t)ca * WROW;
        float pb2 = b2[cb], pe = b2[ce], pa = b2[ca];
#pragma unroll
        for (int k = 0; k < KH; k++) {
            pb2 += hv[k] * wb2[k];
            pe  += hv[k] * we[k];
            pa  += hv[k] * wa[k];
        }
        pe *= 0.1f;   // eps
        pa *= 0.1f;   // alpha
        float sig = 1.0f / (1.0f + __expf(-pe));
        float y = __expf(pa) * (xd + 0.8f * sig * num / den) + pb2;
        out[(size_t)sample * 64 + out_off + d] = y;
    }
}

extern "C" void kernel_launch(void* const* d_in, const int* in_sizes, int n_in,
                              void* d_out, int out_size, void* d_ws, size_t ws_size,
                              hipStream_t stream) {
    const float* x    = (const float*)d_in[0];
    const float* s1W1 = (const float*)d_in[1];
    const float* s1b1 = (const float*)d_in[2];
    const float* s1W2 = (const float*)d_in[3];
    const float* s1b2 = (const float*)d_in[4];
    const float* s2W1 = (const float*)d_in[5];
    const float* s2b1 = (const float*)d_in[6];
    const float* s2W2 = (const float*)d_in[7];
    const float* s2b2 = (const float*)d_in[8];
    float* out = (float*)d_out;

    float* W2T1 = (float*)d_ws;
    float* W2T2 = W2T1 + (size_t)PCOLS * WROW;
    float* h    = W2T2 + (size_t)PCOLS * WROW;

    int tb = (PCOLS * WROW + 255) / 256;
    transpose_pad<<<tb, 256, 0, stream>>>(s1W2, W2T1);
    transpose_pad<<<tb, 256, 0, stream>>>(s2W2, W2T2);

    // subnet 1: cond = x2 (cols 32..63), x = x1 (cols 0..31), out cols 0..31
    h_kernel<<<NB / 256, 256, 0, stream>>>(x, DIM, s1W1, s1b1, h);
    y_kernel<<<dim3(NB / 64, DIM / 2), 64, 0, stream>>>(x, 0, h, W2T1, s1b2, out, 0);

    // subnet 2: cond = y1 (out cols 0..31), x = x2 (cols 32..63), out cols 32..63
    h_kernel<<<NB / 256, 256, 0, stream>>>(out, 0, s2W1, s2b1, h);
    y_kernel<<<dim3(NB / 64, DIM / 2), 64, 0, stream>>>(x, DIM, h, W2T2, s2b2, out, DIM);
}

// Round 2
// 297.076 us; speedup vs baseline: 6.3335x; 6.3335x over previous
//
#include <hip/hip_runtime.h>
#include <hip/hip_bf16.h>

#define NB 16384
#define DIM 32
#define LS 100
#define KH 50
#define PCOLS 9696       // 3*DIM*LS + 3*DIM
#define LPAD 112         // LS padded to 7*16
#define DSTRIDE 336      // 3*LPAD columns per output dim
#define NCR (DIM * DSTRIDE)  // 10752 reordered columns
#define KPAD 64          // K padded: 50 real + 1 bias row + 13 zero

typedef __attribute__((ext_vector_type(4))) float f32x4;
typedef __attribute__((ext_vector_type(8))) short short8;

static __device__ __forceinline__ unsigned short f2bf(float f) {
    __hip_bfloat16 h = __float2bfloat16(f);
    return *reinterpret_cast<unsigned short*>(&h);
}
static __device__ __forceinline__ float bf2f(unsigned short u) {
    __hip_bfloat16 h = *reinterpret_cast<__hip_bfloat16*>(&u);
    return __bfloat162float(h);
}

// ---- reorder + pad + bf16-ify W2, folding b2 in as the k=50 row ----
// W2R[c'][k], c' = d*336 + t*112 + l  (orig col = t*3200 + d*100 + l)
__global__ __launch_bounds__(256) void prep_w2r(const float* __restrict__ W2,
                                                const float* __restrict__ b2,
                                                unsigned short* __restrict__ W2R) {
    int idx = blockIdx.x * 256 + threadIdx.x;   // = c'*64 + k
    if (idx >= NCR * KPAD) return;
    int cp = idx >> 6;
    int k  = idx & 63;
    int d   = cp / DSTRIDE;
    int rem = cp - d * DSTRIDE;
    int t   = rem / LPAD;
    int l   = rem - t * LPAD;
    float v = 0.0f;
    if (l < LS) {
        int col = t * (DIM * LS) + d * LS + l;
        if (k < KH)       v = W2[k * PCOLS + col];
        else if (k == KH) v = b2[col];
    }
    W2R[idx] = f2bf(v);
}

// ---- h = relu(cond @ W1 + b1) -> bf16 [NB][64], with h[50]=1 (bias hook) ----
__global__ __launch_bounds__(64) void h_kernel(const float* __restrict__ cond, int cond_off,
                                               const float* __restrict__ W1,
                                               const float* __restrict__ b1,
                                               unsigned short* __restrict__ hb) {
    int i = blockIdx.x * 64 + threadIdx.x;   // sample
    const float* crow = cond + (size_t)i * 64 + cond_off;
    float c[DIM];
#pragma unroll
    for (int j = 0; j < DIM; j++) c[j] = crow[j];
    unsigned short* hrow = hb + (size_t)i * KPAD;
    for (int k = 0; k < KH; k++) {
        float acc = b1[k];
#pragma unroll
        for (int j = 0; j < DIM; j++) acc += c[j] * W1[j * KH + k];
        hrow[k] = f2bf(fmaxf(acc, 0.0f));
    }
    hrow[KH] = f2bf(1.0f);
#pragma unroll
    for (int k = KH + 1; k < KPAD; k++) hrow[k] = 0;
}

// ---- tail params: bias2, sigE = 0.8*sigmoid(eps/10), alphaE = exp(alpha/10) ----
__global__ __launch_bounds__(256) void tail_kernel(const unsigned short* __restrict__ hb,
                                                   const float* __restrict__ W2,
                                                   const float* __restrict__ b2,
                                                   float* __restrict__ tB,
                                                   float* __restrict__ tS,
                                                   float* __restrict__ tA) {
    int t = blockIdx.x * 256 + threadIdx.x;   // t = s*32 + d
    int s = t >> 5;
    int d = t & 31;
    float h[KH];
    const unsigned short* hrow = hb + (size_t)s * KPAD;
#pragma unroll
    for (int k = 0; k < KH; k++) h[k] = bf2f(hrow[k]);
    int cb = 3 * DIM * LS + d, ce = cb + DIM, ca = ce + DIM;
    float pb = b2[cb], pe = b2[ce], pa = b2[ca];
    for (int k = 0; k < KH; k++) {
        const float* wr = W2 + (size_t)k * PCOLS;
        pb = fmaf(h[k], wr[cb], pb);
        pe = fmaf(h[k], wr[ce], pe);
        pa = fmaf(h[k], wr[ca], pa);
    }
    tB[t] = pb;
    tS[t] = 0.8f / (1.0f + __expf(-pe * 0.1f));
    tA[t] = __expf(pa * 0.1f);
}

// ---- fused p-GEMM (MFMA) + PfndELU epilogue. 1 wave = 32 samples x 1 dim ----
__global__ __launch_bounds__(64) void y_mfma(const float* __restrict__ x, int x_off,
                                             const unsigned short* __restrict__ hb,
                                             const unsigned short* __restrict__ W2R,
                                             const float* __restrict__ tB,
                                             const float* __restrict__ tS,
                                             const float* __restrict__ tA,
                                             float* __restrict__ out, int out_off) {
    int lane = threadIdx.x;
    int c = lane & 15, g = lane >> 4;
    int m0 = blockIdx.x * 32;
    int d  = blockIdx.y;

    // A fragments: rows = samples (lane&15), k = 8 contiguous bf16 at 8*(lane>>4)
    short8 af[2][2];
#pragma unroll
    for (int mt = 0; mt < 2; mt++)
#pragma unroll
        for (int ks = 0; ks < 2; ks++)
            af[mt][ks] = *reinterpret_cast<const short8*>(
                hb + (size_t)(m0 + mt * 16 + c) * KPAD + ks * 32 + g * 8);

    // x values for the 8 accumulator rows this lane owns
    float xv[2][4];
#pragma unroll
    for (int mt = 0; mt < 2; mt++)
#pragma unroll
        for (int r = 0; r < 4; r++)
            xv[mt][r] = x[(size_t)(m0 + mt * 16 + g * 4 + r) * 64 + x_off + d];

    float num[2][4] = {{0.f,0.f,0.f,0.f},{0.f,0.f,0.f,0.f}};
    float den[2][4] = {{0.f,0.f,0.f,0.f},{0.f,0.f,0.f,0.f}};
    const unsigned short* wbase = W2R + (size_t)d * DSTRIDE * KPAD;

    for (int j = 0; j < 7; j++) {
        short8 bf[3][2];
#pragma unroll
        for (int t = 0; t < 3; t++)
#pragma unroll
            for (int ks = 0; ks < 2; ks++)
                bf[t][ks] = *reinterpret_cast<const short8*>(
                    wbase + (size_t)(t * LPAD + j * 16 + c) * KPAD + ks * 32 + g * 8);
#pragma unroll
        for (int mt = 0; mt < 2; mt++) {
            f32x4 a1 = {0.f, 0.f, 0.f, 0.f};
            f32x4 a2 = {0.f, 0.f, 0.f, 0.f};
            f32x4 a3 = {0.f, 0.f, 0.f, 0.f};
            a1 = __builtin_amdgcn_mfma_f32_16x16x32_bf16(af[mt][0], bf[0][0], a1, 0, 0, 0);
            a1 = __builtin_amdgcn_mfma_f32_16x16x32_bf16(af[mt][1], bf[0][1], a1, 0, 0, 0);
            a2 = __builtin_amdgcn_mfma_f32_16x16x32_bf16(af[mt][0], bf[1][0], a2, 0, 0, 0);
            a2 = __builtin_amdgcn_mfma_f32_16x16x32_bf16(af[mt][1], bf[1][1], a2, 0, 0, 0);
            a3 = __builtin_amdgcn_mfma_f32_16x16x32_bf16(af[mt][0], bf[2][0], a3, 0, 0, 0);
            a3 = __builtin_amdgcn_mfma_f32_16x16x32_bf16(af[mt][1], bf[2][1], a3, 0, 0, 0);
#pragma unroll
            for (int r = 0; r < 4; r++) {
                float m1 = a1[r], bb = a2[r], m2 = a3[r];
                float z = fmaf(xv[mt][r], m1, bb);
                float e = (z > 0.f) ? z : (__expf(z) - 1.0f);   // elu
                num[mt][r] = fmaf(e, m2, num[mt][r]);
                den[mt][r] += fmaxf(-m1 * m2, 0.f);             // relu
            }
        }
    }

    // reduce num/den over the 16 lanes (l = j*16 + c) of each lane-group
#pragma unroll
    for (int mt = 0; mt < 2; mt++)
#pragma unroll
        for (int r = 0; r < 4; r++) {
            float n = num[mt][r], dn = den[mt][r];
#pragma unroll
            for (int mask = 1; mask < 16; mask <<= 1) {
                n  += __shfl_xor(n, mask);
                dn += __shfl_xor(dn, mask);
            }
            num[mt][r] = n;
            den[mt][r] = dn;
        }

    // final y, one writer lane per row
#pragma unroll
    for (int mt = 0; mt < 2; mt++)
#pragma unroll
        for (int r = 0; r < 4; r++) {
            int s = m0 + mt * 16 + g * 4 + r;
            int ti = s * 32 + d;
            float y = tA[ti] * (xv[mt][r] + tS[ti] * num[mt][r] / (den[mt][r] + 1.0f)) + tB[ti];
            if (c == r) out[(size_t)s * 64 + out_off + d] = y;
        }
}

extern "C" void kernel_launch(void* const* d_in, const int* in_sizes, int n_in,
                              void* d_out, int out_size, void* d_ws, size_t ws_size,
                              hipStream_t stream) {
    const float* x    = (const float*)d_in[0];
    const float* s1W1 = (const float*)d_in[1];
    const float* s1b1 = (const float*)d_in[2];
    const float* s1W2 = (const float*)d_in[3];
    const float* s1b2 = (const float*)d_in[4];
    const float* s2W1 = (const float*)d_in[5];
    const float* s2b1 = (const float*)d_in[6];
    const float* s2W2 = (const float*)d_in[7];
    const float* s2b2 = (const float*)d_in[8];
    float* out = (float*)d_out;

    char* ws = (char*)d_ws;
    unsigned short* W2R1 = (unsigned short*)ws;                 ws += (size_t)NCR * KPAD * 2;
    unsigned short* W2R2 = (unsigned short*)ws;                 ws += (size_t)NCR * KPAD * 2;
    unsigned short* hb   = (unsigned short*)ws;                 ws += (size_t)NB * KPAD * 2;
    float* tB = (float*)ws;                                     ws += (size_t)NB * 32 * 4;
    float* tS = (float*)ws;                                     ws += (size_t)NB * 32 * 4;
    float* tA = (float*)ws;

    int pb = (NCR * KPAD + 255) / 256;
    prep_w2r<<<pb, 256, 0, stream>>>(s1W2, s1b2, W2R1);
    prep_w2r<<<pb, 256, 0, stream>>>(s2W2, s2b2, W2R2);

    // subnet 1: cond = x2 (cols 32..63), x = x1 (cols 0..31), out cols 0..31
    h_kernel<<<NB / 64, 64, 0, stream>>>(x, DIM, s1W1, s1b1, hb);
    tail_kernel<<<NB * 32 / 256, 256, 0, stream>>>(hb, s1W2, s1b2, tB, tS, tA);
    y_mfma<<<dim3(NB / 32, DIM), 64, 0, stream>>>(x, 0, hb, W2R1, tB, tS, tA, out, 0);

    // subnet 2: cond = y1 (out cols 0..31), x = x2 (cols 32..63), out cols 32..63
    h_kernel<<<NB / 64, 64, 0, stream>>>(out, 0, s2W1, s2b1, hb);
    tail_kernel<<<NB * 32 / 256, 256, 0, stream>>>(hb, s2W2, s2b2, tB, tS, tA);
    y_mfma<<<dim3(NB / 32, DIM), 64, 0, stream>>>(x, DIM, hb, W2R2, tB, tS, tA, out, DIM);
}

// Round 3
// 240.150 us; speedup vs baseline: 7.8348x; 1.2370x over previous
//
#include <hip/hip_runtime.h>
#include <hip/hip_bf16.h>

#define NB 16384
#define DIM 32
#define LS 100
#define KH 50
#define PCOLS 9696       // 3*DIM*LS + 3*DIM
#define LPAD 112         // LS padded to 7*16
#define DSTRIDE 336      // 3*LPAD columns per output dim
#define NCR (DIM * DSTRIDE)  // 10752 reordered columns
#define KPAD 64          // K padded: 50 real + 1 bias row + 13 zero

typedef __attribute__((ext_vector_type(4))) float f32x4;
typedef __attribute__((ext_vector_type(8))) short short8;

static __device__ __forceinline__ unsigned short f2bf(float f) {
    __hip_bfloat16 h = __float2bfloat16(f);
    return *reinterpret_cast<unsigned short*>(&h);
}

// ---- reorder + pad + bf16-ify W2 (b2 folded as k=50 row), LDS transpose ----
// W2R[c'][k], c' = d*336 + t*112 + l  (orig col = t*3200 + d*100 + l)
__global__ __launch_bounds__(256) void prep_w2r(const float* __restrict__ W2,
                                                const float* __restrict__ b2,
                                                unsigned short* __restrict__ W2R) {
    __shared__ unsigned short tile[64][66];   // +2 pad: bank = (cl*33+k/2)&31, conflict-free
    int cb = blockIdx.x * 64;                 // c' base (168 blocks)
    int tid = threadIdx.x;

    // phase 1: coalesced reads (consecutive threads -> consecutive cols)
    int cl = tid & 63;
    int kg = tid >> 6;                        // 0..3
    int cp = cb + cl;
    int d   = cp / DSTRIDE;
    int rem = cp - d * DSTRIDE;
    int t   = rem / LPAD;
    int l   = rem - t * LPAD;
    int col = t * (DIM * LS) + d * LS + l;
    bool valid = (l < LS);
#pragma unroll
    for (int kk = 0; kk < 16; kk++) {
        int k = kg * 16 + kk;                 // 0..63
        float v = 0.0f;
        if (valid) {
            if (k < KH)       v = W2[(size_t)k * PCOLS + col];
            else if (k == KH) v = b2[col];
        }
        tile[cl][k] = f2bf(v);
    }
    __syncthreads();

    // phase 2: coalesced writes (consecutive threads -> consecutive k)
    int k  = tid & 63;
    int cg = tid >> 6;
#pragma unroll
    for (int ii = 0; ii < 16; ii++) {
        int cl2 = cg * 16 + ii;
        W2R[(size_t)(cb + cl2) * KPAD + k] = tile[cl2][k];
    }
}

// ---- h = relu(cond @ W1 + b1) -> bf16 [NB][64]; h[50]=1 (bias hook), rest 0 ----
__global__ __launch_bounds__(256) void h_kernel(const float* __restrict__ cond, int cond_off,
                                                const float* __restrict__ W1,
                                                const float* __restrict__ b1,
                                                unsigned short* __restrict__ hb) {
    int idx = blockIdx.x * 256 + threadIdx.x;   // = s*64 + k
    int s = idx >> 6, k = idx & 63;
    float v;
    if (k < KH) {
        const float* crow = cond + (size_t)s * 64 + cond_off;   // wave-uniform -> s_load
        float acc = b1[k];
#pragma unroll
        for (int j = 0; j < DIM; j++) acc = fmaf(crow[j], W1[j * KH + k], acc);
        v = fmaxf(acc, 0.0f);
    } else {
        v = (k == KH) ? 1.0f : 0.0f;
    }
    hb[idx] = f2bf(v);
}

// ---- tail params: bias2, sigE = 0.8*sigmoid(eps/10), alphaE = exp(alpha/10) ----
__global__ __launch_bounds__(256) void tail_kernel(const unsigned short* __restrict__ hb,
                                                   const float* __restrict__ W2,
                                                   const float* __restrict__ b2,
                                                   float* __restrict__ tB,
                                                   float* __restrict__ tS,
                                                   float* __restrict__ tA) {
    int t = blockIdx.x * 256 + threadIdx.x;   // t = s*32 + d
    int s = t >> 5;
    int d = t & 31;
    float h[KH];
    const unsigned short* hrow = hb + (size_t)s * KPAD;
#pragma unroll
    for (int k = 0; k < KH; k++) {
        unsigned short u = hrow[k];
        __hip_bfloat16 bh = *reinterpret_cast<__hip_bfloat16*>(&u);
        h[k] = __bfloat162float(bh);
    }
    int cb = 3 * DIM * LS + d, ce = cb + DIM, ca = ce + DIM;
    float pb = b2[cb], pe = b2[ce], pa = b2[ca];
    for (int k = 0; k < KH; k++) {
        const float* wr = W2 + (size_t)k * PCOLS;
        pb = fmaf(h[k], wr[cb], pb);
        pe = fmaf(h[k], wr[ce], pe);
        pa = fmaf(h[k], wr[ca], pa);
    }
    tB[t] = pb;
    tS[t] = 0.8f / (1.0f + __expf(-pe * 0.1f));
    tA[t] = __expf(pa * 0.1f);
}

// ---- fused p-GEMM (MFMA) + PfndELU epilogue ----
// 256-thread block = 4 waves; each wave: 64 samples (MT=4 row-tiles) x 1 dim.
__global__ __launch_bounds__(256) void y_mfma(const float* __restrict__ x, int x_off,
                                              const unsigned short* __restrict__ hb,
                                              const unsigned short* __restrict__ W2R,
                                              const float* __restrict__ tB,
                                              const float* __restrict__ tS,
                                              const float* __restrict__ tA,
                                              float* __restrict__ out, int out_off) {
    int lane = threadIdx.x & 63;
    int wave = threadIdx.x >> 6;
    int c = lane & 15, g = lane >> 4;
    int m0 = (blockIdx.x * 4 + wave) * 64;    // 64 samples per wave
    int d  = blockIdx.y;

    // A fragments: rows = samples, k = 8 contiguous bf16 at 16B*(lane>>4)
    short8 af[4][2];
#pragma unroll
    for (int mt = 0; mt < 4; mt++)
#pragma unroll
        for (int ks = 0; ks < 2; ks++)
            af[mt][ks] = *reinterpret_cast<const short8*>(
                hb + (size_t)(m0 + mt * 16 + c) * KPAD + ks * 32 + g * 8);

    float xv[4][4];
#pragma unroll
    for (int mt = 0; mt < 4; mt++)
#pragma unroll
        for (int r = 0; r < 4; r++)
            xv[mt][r] = x[(size_t)(m0 + mt * 16 + g * 4 + r) * 64 + x_off + d];

    float num[4][4] = {};
    float den[4][4] = {};
    const unsigned short* wbase = W2R + (size_t)d * DSTRIDE * KPAD;

    short8 bfA[3][2], bfB[3][2];
    auto loadB = [&](short8 (&dst)[3][2], int j) {
#pragma unroll
        for (int t = 0; t < 3; t++)
#pragma unroll
            for (int ks = 0; ks < 2; ks++)
                dst[t][ks] = *reinterpret_cast<const short8*>(
                    wbase + (size_t)(t * LPAD + j * 16 + c) * KPAD + ks * 32 + g * 8);
    };
    auto computeJ = [&](const short8 (&bf)[3][2]) {
#pragma unroll
        for (int mt = 0; mt < 4; mt++) {
            f32x4 a1 = {0.f, 0.f, 0.f, 0.f};
            f32x4 a2 = {0.f, 0.f, 0.f, 0.f};
            f32x4 a3 = {0.f, 0.f, 0.f, 0.f};
            a1 = __builtin_amdgcn_mfma_f32_16x16x32_bf16(af[mt][0], bf[0][0], a1, 0, 0, 0);
            a1 = __builtin_amdgcn_mfma_f32_16x16x32_bf16(af[mt][1], bf[0][1], a1, 0, 0, 0);
            a2 = __builtin_amdgcn_mfma_f32_16x16x32_bf16(af[mt][0], bf[1][0], a2, 0, 0, 0);
            a2 = __builtin_amdgcn_mfma_f32_16x16x32_bf16(af[mt][1], bf[1][1], a2, 0, 0, 0);
            a3 = __builtin_amdgcn_mfma_f32_16x16x32_bf16(af[mt][0], bf[2][0], a3, 0, 0, 0);
            a3 = __builtin_amdgcn_mfma_f32_16x16x32_bf16(af[mt][1], bf[2][1], a3, 0, 0, 0);
#pragma unroll
            for (int r = 0; r < 4; r++) {
                float m1 = a1[r], bb = a2[r], m2 = a3[r];
                float z = fmaf(xv[mt][r], m1, bb);
                float e = (z > 0.f) ? z : (__expf(z) - 1.0f);   // elu
                num[mt][r] = fmaf(e, m2, num[mt][r]);
                den[mt][r] += fmaxf(-m1 * m2, 0.f);             // relu
            }
        }
    };

    // fully-unrolled 7-step schedule, 2-deep B prefetch
    loadB(bfA, 0);
    loadB(bfB, 1);
    computeJ(bfA); loadB(bfA, 2);
    computeJ(bfB); loadB(bfB, 3);
    computeJ(bfA); loadB(bfA, 4);
    computeJ(bfB); loadB(bfB, 5);
    computeJ(bfA); loadB(bfA, 6);
    computeJ(bfB);
    computeJ(bfA);

    // reduce num/den over the 16 l-lanes of each g-group
#pragma unroll
    for (int mt = 0; mt < 4; mt++)
#pragma unroll
        for (int r = 0; r < 4; r++) {
            float n = num[mt][r], dn = den[mt][r];
#pragma unroll
            for (int mask = 1; mask < 16; mask <<= 1) {
                n  += __shfl_xor(n, mask);
                dn += __shfl_xor(dn, mask);
            }
            num[mt][r] = n;
            den[mt][r] = dn;
        }

    // final y, one writer lane per row (c == r, g spans rows)
#pragma unroll
    for (int mt = 0; mt < 4; mt++)
#pragma unroll
        for (int r = 0; r < 4; r++) {
            if (c == r) {
                int s = m0 + mt * 16 + g * 4 + r;
                int ti = s * 32 + d;
                float y = tA[ti] * (xv[mt][r] + tS[ti] * __fdividef(num[mt][r], den[mt][r] + 1.0f)) + tB[ti];
                out[(size_t)s * 64 + out_off + d] = y;
            }
        }
}

extern "C" void kernel_launch(void* const* d_in, const int* in_sizes, int n_in,
                              void* d_out, int out_size, void* d_ws, size_t ws_size,
                              hipStream_t stream) {
    const float* x    = (const float*)d_in[0];
    const float* s1W1 = (const float*)d_in[1];
    const float* s1b1 = (const float*)d_in[2];
    const float* s1W2 = (const float*)d_in[3];
    const float* s1b2 = (const float*)d_in[4];
    const float* s2W1 = (const float*)d_in[5];
    const float* s2b1 = (const float*)d_in[6];
    const float* s2W2 = (const float*)d_in[7];
    const float* s2b2 = (const float*)d_in[8];
    float* out = (float*)d_out;

    char* ws = (char*)d_ws;
    unsigned short* W2R1 = (unsigned short*)ws;                 ws += (size_t)NCR * KPAD * 2;
    unsigned short* W2R2 = (unsigned short*)ws;                 ws += (size_t)NCR * KPAD * 2;
    unsigned short* hb   = (unsigned short*)ws;                 ws += (size_t)NB * KPAD * 2;
    float* tB = (float*)ws;                                     ws += (size_t)NB * 32 * 4;
    float* tS = (float*)ws;                                     ws += (size_t)NB * 32 * 4;
    float* tA = (float*)ws;

    prep_w2r<<<NCR / 64, 256, 0, stream>>>(s1W2, s1b2, W2R1);
    prep_w2r<<<NCR / 64, 256, 0, stream>>>(s2W2, s2b2, W2R2);

    // subnet 1: cond = x2 (cols 32..63), x = x1 (cols 0..31), out cols 0..31
    h_kernel<<<NB * 64 / 256, 256, 0, stream>>>(x, DIM, s1W1, s1b1, hb);
    tail_kernel<<<NB * 32 / 256, 256, 0, stream>>>(hb, s1W2, s1b2, tB, tS, tA);
    y_mfma<<<dim3(NB / 256, DIM), 256, 0, stream>>>(x, 0, hb, W2R1, tB, tS, tA, out, 0);

    // subnet 2: cond = y1 (out cols 0..31), x = x2 (cols 32..63), out cols 32..63
    h_kernel<<<NB * 64 / 256, 256, 0, stream>>>(out, 0, s2W1, s2b1, hb);
    tail_kernel<<<NB * 32 / 256, 256, 0, stream>>>(hb, s2W2, s2b2, tB, tS, tA);
    y_mfma<<<dim3(NB / 256, DIM), 256, 0, stream>>>(x, DIM, hb, W2R2, tB, tS, tA, out, DIM);
}

// Round 4
// 187.809 us; speedup vs baseline: 10.0183x; 1.2787x over previous
//
#include <hip/hip_runtime.h>
#include <hip/hip_bf16.h>

#define NB 16384
#define DIM 32
#define LS 100
#define KH 50
#define PCOLS 9696           // 3*DIM*LS + 3*DIM
#define LPAD 112             // LS padded to 7*16
#define DSTRIDE 352          // 3*LPAD + 16 tail slots (bias2, eps, alpha, 13 zero)
#define NCR (DIM * DSTRIDE)  // 11264 reordered columns
#define KPAD 64              // 50 real + 1 bias row + 13 zero
#define BPD (DSTRIDE * KPAD) // 22528 ushorts = 45056 B per output dim
#define PREPB (NCR / 64)     // 176 prep blocks per subnet

typedef __attribute__((ext_vector_type(4))) float f32x4;
typedef __attribute__((ext_vector_type(8))) short short8;

static __device__ __forceinline__ unsigned short f2bf(float f) {
    __hip_bfloat16 h = __float2bfloat16(f);
    return *reinterpret_cast<unsigned short*>(&h);
}

// ---- reorder + pad + bf16 + XOR-swizzle W2 (b2 folded as k=50 row) ----
// logical layout: W2R[row][k], row = d*352 + q; q<336: q=t*112+l (orig col
// t*3200+d*100+l); q in 336..338: tail cols 9600/9632/9664 + d.
// stored k-index is swizzled: sk = k ^ ((row&7)<<3)  (matches y_mfma ds_read)
static __device__ __forceinline__ void prep_body(int bx, const float* __restrict__ W2,
                                                 const float* __restrict__ b2,
                                                 unsigned short* __restrict__ W2R,
                                                 unsigned short (&tile)[64][66]) {
    int cb = bx * 64;
    int tid = threadIdx.x;
    // phase 1: coalesced reads (consecutive threads -> consecutive cols)
    int cl = tid & 63;
    int kg = tid >> 6;
    int cp = cb + cl;
    int d = cp / DSTRIDE;
    int q = cp - d * DSTRIDE;
    int col;
    bool valid;
    if (q < 3 * LPAD) {
        int t = q / LPAD;
        int l = q - t * LPAD;
        col = t * (DIM * LS) + d * LS + l;
        valid = (l < LS);
    } else {
        int e = q - 3 * LPAD;
        col = 3 * DIM * LS + e * DIM + d;
        valid = (e < 3);
    }
#pragma unroll
    for (int kk = 0; kk < 16; kk++) {
        int k = kg * 16 + kk;
        float v = 0.0f;
        if (valid) {
            if (k < KH)       v = W2[(size_t)k * PCOLS + col];
            else if (k == KH) v = b2[col];
        }
        tile[cl][k] = f2bf(v);
    }
    __syncthreads();
    // phase 2: coalesced swizzled writes (consecutive threads -> consecutive k)
    int k = tid & 63;
    int cg = tid >> 6;
#pragma unroll
    for (int ii = 0; ii < 16; ii++) {
        int lr = cg * 16 + ii;
        int row = cb + lr;
        W2R[(size_t)row * KPAD + (k ^ ((row & 7) << 3))] = tile[lr][k];
    }
}

// ---- h = relu(cond @ W1 + b1) -> bf16 [NB][64]; h[50]=1 (bias hook) ----
static __device__ __forceinline__ void h_body(int bx, const float* __restrict__ cond,
                                              int cond_off, const float* __restrict__ W1,
                                              const float* __restrict__ b1,
                                              unsigned short* __restrict__ hb) {
    int idx = bx * 256 + threadIdx.x;   // = s*64 + k; s is wave-uniform
    int s = idx >> 6, k = idx & 63;
    float v;
    if (k < KH) {
        const float* crow = cond + (size_t)s * 64 + cond_off;
        float acc = b1[k];
#pragma unroll
        for (int j = 0; j < DIM; j++) acc = fmaf(crow[j], W1[j * KH + k], acc);
        v = fmaxf(acc, 0.0f);
    } else {
        v = (k == KH) ? 1.0f : 0.0f;
    }
    hb[idx] = f2bf(v);
}

// ---- combined: prep both subnets' W2R + h1 (all independent) ----
__global__ __launch_bounds__(256) void combo_kernel(const float* __restrict__ W2a,
                                                    const float* __restrict__ b2a,
                                                    unsigned short* __restrict__ W2Ra,
                                                    const float* __restrict__ W2b,
                                                    const float* __restrict__ b2b,
                                                    unsigned short* __restrict__ W2Rb,
                                                    const float* __restrict__ x,
                                                    const float* __restrict__ W1,
                                                    const float* __restrict__ b1,
                                                    unsigned short* __restrict__ hb) {
    __shared__ unsigned short tile[64][66];
    int b = blockIdx.x;
    if (b < 2 * PREPB) {
        if (b < PREPB) prep_body(b, W2a, b2a, W2Ra, tile);
        else           prep_body(b - PREPB, W2b, b2b, W2Rb, tile);
    } else {
        h_body(b - 2 * PREPB, x, DIM, W1, b1, hb);   // cond = x2
    }
}

__global__ __launch_bounds__(256) void h_kernel(const float* __restrict__ cond, int cond_off,
                                                const float* __restrict__ W1,
                                                const float* __restrict__ b1,
                                                unsigned short* __restrict__ hb) {
    h_body(blockIdx.x, cond, cond_off, W1, b1, hb);
}

// ---- fused p-GEMM (MFMA, LDS B-panel) + PfndELU epilogue + tail params ----
// 256-thread block = 4 waves sharing one d; each wave: 64 samples (MT=4).
__global__ __launch_bounds__(256) void y_mfma(const float* __restrict__ x, int x_off,
                                              const unsigned short* __restrict__ hb,
                                              const unsigned short* __restrict__ W2R,
                                              float* __restrict__ out, int out_off) {
    __shared__ unsigned short lB[BPD];   // 45056 B
    int tid = threadIdx.x;
    int lane = tid & 63, wave = tid >> 6;
    int c = lane & 15, g = lane >> 4;
    int d = blockIdx.y;
    int m0 = (blockIdx.x * 4 + wave) * 64;

    // async-stage the whole B panel; global layout is pre-swizzled so the
    // copy is strictly linear (rule 21: linear dest + pre-swizzled source)
    {
        const char* src = (const char*)(W2R + (size_t)d * BPD);
        char* dst = (char*)lB;
#pragma unroll
        for (int i = 0; i < 11; i++) {
            int chunk = wave * 11 + i;
            __builtin_amdgcn_global_load_lds(
                (const __attribute__((address_space(1))) void*)(src + chunk * 1024 + lane * 16),
                (__attribute__((address_space(3))) void*)(dst + chunk * 1024),
                16, 0, 0);
        }
    }

    // A fragments + x loads overlap the staging
    short8 af[4][2];
#pragma unroll
    for (int mt = 0; mt < 4; mt++)
#pragma unroll
        for (int ks = 0; ks < 2; ks++)
            af[mt][ks] = *reinterpret_cast<const short8*>(
                hb + (size_t)(m0 + mt * 16 + c) * KPAD + ks * 32 + g * 8);

    float xv[4][4];
#pragma unroll
    for (int mt = 0; mt < 4; mt++)
#pragma unroll
        for (int r = 0; r < 4; r++)
            xv[mt][r] = x[(size_t)(m0 + mt * 16 + g * 4 + r) * 64 + x_off + d];

    asm volatile("s_waitcnt vmcnt(0)" ::: "memory");
    __syncthreads();

    const char* lbB = (const char*)lB;
    // swizzled read: row's 16B slot (ks*4+g) XORed with (row&7)==(c&7)
    auto ldB = [&](int row, int ks) -> short8 {
        int slot = (ks * 4 + g) ^ (c & 7);
        return *reinterpret_cast<const short8*>(lbB + row * 128 + slot * 16);
    };

    float num[4][4] = {};
    float den[4][4] = {};
#pragma unroll
    for (int j = 0; j < 7; j++) {
        int r0 = j * 16 + c;
        short8 b00 = ldB(r0, 0),            b01 = ldB(r0, 1);
        short8 b10 = ldB(r0 + LPAD, 0),     b11 = ldB(r0 + LPAD, 1);
        short8 b20 = ldB(r0 + 2 * LPAD, 0), b21 = ldB(r0 + 2 * LPAD, 1);
#pragma unroll
        for (int mt = 0; mt < 4; mt++) {
            f32x4 a1 = {0.f, 0.f, 0.f, 0.f};
            f32x4 a2 = {0.f, 0.f, 0.f, 0.f};
            f32x4 a3 = {0.f, 0.f, 0.f, 0.f};
            a1 = __builtin_amdgcn_mfma_f32_16x16x32_bf16(af[mt][0], b00, a1, 0, 0, 0);
            a1 = __builtin_amdgcn_mfma_f32_16x16x32_bf16(af[mt][1], b01, a1, 0, 0, 0);
            a2 = __builtin_amdgcn_mfma_f32_16x16x32_bf16(af[mt][0], b10, a2, 0, 0, 0);
            a2 = __builtin_amdgcn_mfma_f32_16x16x32_bf16(af[mt][1], b11, a2, 0, 0, 0);
            a3 = __builtin_amdgcn_mfma_f32_16x16x32_bf16(af[mt][0], b20, a3, 0, 0, 0);
            a3 = __builtin_amdgcn_mfma_f32_16x16x32_bf16(af[mt][1], b21, a3, 0, 0, 0);
#pragma unroll
            for (int r = 0; r < 4; r++) {
                float m1 = a1[r], bb = a2[r], m2 = a3[r];
                float z = fmaf(xv[mt][r], m1, bb);
                float e = (z > 0.f) ? z : (__expf(z) - 1.0f);   // elu
                num[mt][r] = fmaf(e, m2, num[mt][r]);
                den[mt][r] += fmaxf(-m1 * m2, 0.f);             // relu
            }
        }
    }

    // tail params via 2 MFMAs: acc col 0 = bias2, col 1 = eps, col 2 = alpha
    short8 t0 = ldB(3 * LPAD + c, 0), t1 = ldB(3 * LPAD + c, 1);
    f32x4 pt[4];
#pragma unroll
    for (int mt = 0; mt < 4; mt++) {
        f32x4 a = {0.f, 0.f, 0.f, 0.f};
        a = __builtin_amdgcn_mfma_f32_16x16x32_bf16(af[mt][0], t0, a, 0, 0, 0);
        a = __builtin_amdgcn_mfma_f32_16x16x32_bf16(af[mt][1], t1, a, 0, 0, 0);
        pt[mt] = a;
    }

    // reduce num/den over the 16 l-lanes; lane c==0 assembles params & writes
#pragma unroll
    for (int mt = 0; mt < 4; mt++)
#pragma unroll
        for (int r = 0; r < 4; r++) {
            float n = num[mt][r], dn = den[mt][r];
#pragma unroll
            for (int mask = 1; mask < 16; mask <<= 1) {
                n  += __shfl_xor(n, mask);
                dn += __shfl_xor(dn, mask);
            }
            float pb = pt[mt][r];                  // lane c=0 holds bias2
            float pe = __shfl_xor(pt[mt][r], 1);   // lane c=0 <- c=1 (eps)
            float pa = __shfl_xor(pt[mt][r], 2);   // lane c=0 <- c=2 (alpha)
            if (c == 0) {
                float sig = 0.8f / (1.0f + __expf(-pe * 0.1f));
                float y = __expf(pa * 0.1f) * (xv[mt][r] + sig * __fdividef(n, dn + 1.0f)) + pb;
                out[(size_t)(m0 + mt * 16 + g * 4 + r) * 64 + out_off + d] = y;
            }
        }
}

extern "C" void kernel_launch(void* const* d_in, const int* in_sizes, int n_in,
                              void* d_out, int out_size, void* d_ws, size_t ws_size,
                              hipStream_t stream) {
    const float* x    = (const float*)d_in[0];
    const float* s1W1 = (const float*)d_in[1];
    const float* s1b1 = (const float*)d_in[2];
    const float* s1W2 = (const float*)d_in[3];
    const float* s1b2 = (const float*)d_in[4];
    const float* s2W1 = (const float*)d_in[5];
    const float* s2b1 = (const float*)d_in[6];
    const float* s2W2 = (const float*)d_in[7];
    const float* s2b2 = (const float*)d_in[8];
    float* out = (float*)d_out;

    char* ws = (char*)d_ws;
    unsigned short* W2R1 = (unsigned short*)ws;   ws += (size_t)NCR * KPAD * 2;
    unsigned short* W2R2 = (unsigned short*)ws;   ws += (size_t)NCR * KPAD * 2;
    unsigned short* hb1  = (unsigned short*)ws;   ws += (size_t)NB * KPAD * 2;
    unsigned short* hb2  = (unsigned short*)ws;

    // dispatch 1: prep both W2R + h1 (cond = x2)
    combo_kernel<<<2 * PREPB + NB * 64 / 256, 256, 0, stream>>>(
        s1W2, s1b2, W2R1, s2W2, s2b2, W2R2, x, s1W1, s1b1, hb1);
    // dispatch 2: y1 -> out cols 0..31
    y_mfma<<<dim3(NB / 256, DIM), 256, 0, stream>>>(x, 0, hb1, W2R1, out, 0);
    // dispatch 3: h2 (cond = y1)
    h_kernel<<<NB * 64 / 256, 256, 0, stream>>>(out, 0, s2W1, s2b1, hb2);
    // dispatch 4: y2 -> out cols 32..63
    y_mfma<<<dim3(NB / 256, DIM), 256, 0, stream>>>(x, DIM, hb2, W2R2, out, DIM);
}